// Round 1
// baseline (46.564 us; speedup 1.0000x reference)
//
#include <hip/hip_runtime.h>
#include <stdint.h>

#define N_PROP    262144
#define N_GT      128
#define N_ALL     (N_PROP + N_GT)      // 262272
#define NFG_MAX   128
#define NROIS_OUT 512
#define BLK       256
#define NBLOCKS   ((N_ALL + BLK - 1) / BLK)   // 1025

// ---------------- workspace layout (bytes) ----------------
// argmax  : uint16 [N_ALL]      @ 0          (524544 B)
// flag    : uint8  [N_ALL]      @ 524544     (262272 B)
// blockFg : int    [NBLOCKS]    @ 786816
// blockBg : int    [NBLOCKS]    @ 790916
// fgOff   : int    [NBLOCKS]    @ 795016
// bgOff   : int    [NBLOCKS]    @ 799116
// params  : int[3] (NF,NB,LIM)  @ 803216
#define OFF_ARGMAX  0
#define OFF_FLAG    524544
#define OFF_BLOCKFG 786816
#define OFF_BLOCKBG 790916
#define OFF_FGOFF   795016
#define OFF_BGOFF   799116
#define OFF_PARAMS  803216

// K1: per-roi max/argmax IoU vs 128 GT; flags + per-block fg/bg counts.
__global__ __launch_bounds__(BLK) void k_iou(
    const float* __restrict__ rois, const float* __restrict__ gt,
    uint16_t* __restrict__ argmax, uint8_t* __restrict__ flag,
    int* __restrict__ blockFg, int* __restrict__ blockBg)
{
    __shared__ float sgx1[N_GT], sgy1[N_GT], sgx2[N_GT], sgy2[N_GT], sga[N_GT];
    int tid = threadIdx.x;
    for (int j = tid; j < N_GT; j += BLK) {
        float4 g = *reinterpret_cast<const float4*>(gt + 4 * j);
        sgx1[j] = g.x; sgy1[j] = g.y; sgx2[j] = g.z; sgy2[j] = g.w;
        // area_g = (gx2-gx1+1)*(gy2-gy1+1), same rounding as reference
        sga[j] = __fmul_rn(__fadd_rn(__fsub_rn(g.z, g.x), 1.0f),
                           __fadd_rn(__fsub_rn(g.w, g.y), 1.0f));
    }
    __syncthreads();

    int i = blockIdx.x * BLK + tid;
    bool valid = (i < N_ALL);
    float bx1 = 0.f, by1 = 0.f, bx2 = 0.f, by2 = 0.f;
    if (valid) {
        const float* p = (i < N_PROP) ? (rois + 4 * (size_t)i)
                                      : (gt + 4 * (size_t)(i - N_PROP));
        float4 b = *reinterpret_cast<const float4*>(p);
        bx1 = b.x; by1 = b.y; bx2 = b.z; by2 = b.w;
    }
    float area_b = __fmul_rn(__fadd_rn(__fsub_rn(bx2, bx1), 1.0f),
                             __fadd_rn(__fsub_rn(by2, by1), 1.0f));
    float best = -1.0f; int bestj = 0;
    if (valid) {
        #pragma unroll 4
        for (int j = 0; j < N_GT; ++j) {
            float iw = fmaxf(__fadd_rn(__fsub_rn(fminf(bx2, sgx2[j]), fmaxf(bx1, sgx1[j])), 1.0f), 0.0f);
            float ih = fmaxf(__fadd_rn(__fsub_rn(fminf(by2, sgy2[j]), fmaxf(by1, sgy1[j])), 1.0f), 0.0f);
            float inter = __fmul_rn(iw, ih);
            float denom = __fsub_rn(__fadd_rn(area_b, sga[j]), inter);
            float iou = __fdiv_rn(inter, denom);
            if (iou > best) { best = iou; bestj = j; }   // strict > keeps first max (jnp.argmax)
        }
    }
    bool fg = valid && (best > 0.5f);
    bool bg = valid && (best > 0.1f) && (best < 0.5f);
    if (valid) {
        argmax[i] = (uint16_t)bestj;
        flag[i]   = fg ? (uint8_t)0 : (bg ? (uint8_t)1 : (uint8_t)2);
    }
    unsigned long long mf = __ballot(fg ? 1 : 0);
    unsigned long long mb = __ballot(bg ? 1 : 0);
    __shared__ int sF[BLK / 64], sB[BLK / 64];
    int lane = tid & 63, w = tid >> 6;
    if (lane == 0) { sF[w] = __popcll(mf); sB[w] = __popcll(mb); }
    __syncthreads();
    if (tid == 0) {
        int tf = 0, tb = 0;
        for (int k = 0; k < BLK / 64; ++k) { tf += sF[k]; tb += sB[k]; }
        blockFg[blockIdx.x] = tf;
        blockBg[blockIdx.x] = tb;
    }
}

// K2: single-block scan over NBLOCKS block counts -> exclusive offsets + params.
__global__ __launch_bounds__(BLK) void k_scan(
    const int* __restrict__ blockFg, const int* __restrict__ blockBg,
    int* __restrict__ fgOff, int* __restrict__ bgOff, int* __restrict__ params)
{
    __shared__ int sF[BLK], sB[BLK];
    int tid = threadIdx.x;
    int carryF = 0, carryB = 0;
    for (int base = 0; base < NBLOCKS; base += BLK) {
        int idx = base + tid;
        int f = (idx < NBLOCKS) ? blockFg[idx] : 0;
        int b = (idx < NBLOCKS) ? blockBg[idx] : 0;
        sF[tid] = f; sB[tid] = b;
        __syncthreads();
        for (int off = 1; off < BLK; off <<= 1) {
            int vf = (tid >= off) ? sF[tid - off] : 0;
            int vb = (tid >= off) ? sB[tid - off] : 0;
            __syncthreads();
            sF[tid] += vf; sB[tid] += vb;
            __syncthreads();
        }
        if (idx < NBLOCKS) {
            fgOff[idx] = carryF + sF[tid] - f;   // exclusive
            bgOff[idx] = carryB + sB[tid] - b;
        }
        carryF += sF[BLK - 1];
        carryB += sB[BLK - 1];
        __syncthreads();
    }
    if (tid == 0) {
        int fgTot = carryF, bgTot = carryB;
        int NF  = fgTot < NFG_MAX ? fgTot : NFG_MAX;      // n_fg
        int LIM = NROIS_OUT - NF;                          // bg cum cap
        int NB  = bgTot < LIM ? bgTot : LIM;               // #sel_bg
        params[0] = NF; params[1] = NB; params[2] = LIM;
    }
}

// K3: reconstruct stable-argsort positions; gather + bbox_transform + write.
__global__ __launch_bounds__(BLK) void k_select(
    const float* __restrict__ rois, const float* __restrict__ gt,
    const int* __restrict__ labels,
    const uint16_t* __restrict__ argmax, const uint8_t* __restrict__ flag,
    const int* __restrict__ fgOff, const int* __restrict__ bgOff,
    const int* __restrict__ params, float* __restrict__ out)
{
    int tid = threadIdx.x;
    int i = blockIdx.x * BLK + tid;
    bool valid = (i < N_ALL);
    uint8_t f = valid ? flag[i] : (uint8_t)2;
    bool isfg = valid && (f == 0);
    bool isbg = valid && (f == 1);
    unsigned long long mf = __ballot(isfg ? 1 : 0);
    unsigned long long mb = __ballot(isbg ? 1 : 0);
    int lane = tid & 63, w = tid >> 6;
    unsigned long long lemask = (lane == 63) ? ~0ull : ((1ull << (lane + 1)) - 1ull);
    int inclF = __popcll(mf & lemask);   // fg count in block up to & incl me
    int inclB = __popcll(mb & lemask);
    __shared__ int sF[BLK / 64], sB[BLK / 64];
    if (lane == 0) { sF[w] = __popcll(mf); sB[w] = __popcll(mb); }
    __syncthreads();
    int preF = 0, preB = 0;
    for (int k = 0; k < w; ++k) { preF += sF[k]; preB += sB[k]; }
    if (!valid) return;

    int fgCum = fgOff[blockIdx.x] + preF + inclF;   // inclusive global fg cumsum at i
    int bgCum = bgOff[blockIdx.x] + preB + inclB;
    int NF = params[0], NB = params[1], LIM = params[2];

    int pos;
    if (isfg && fgCum <= NFG_MAX) {
        pos = fgCum - 1;
    } else if (isbg && bgCum <= LIM) {
        pos = NF + bgCum - 1;
    } else {
        int selF = fgCum < NFG_MAX ? fgCum : NFG_MAX;
        int selB = bgCum < LIM ? bgCum : LIM;
        int restCum = (i + 1) - selF - selB;        // inclusive rank among "rest"
        pos = NF + NB + restCum - 1;
    }
    if (pos >= NROIS_OUT) return;

    const float* rp = (i < N_PROP) ? (rois + 4 * (size_t)i)
                                   : (gt + 4 * (size_t)(i - N_PROP));
    float4 r = *reinterpret_cast<const float4*>(rp);
    int g = argmax[i];
    float4 gb = *reinterpret_cast<const float4*>(gt + 4 * (size_t)g);

    float wdt = __fadd_rn(__fsub_rn(r.z, r.x), 1.0f);
    float hgt = __fadd_rn(__fsub_rn(r.w, r.y), 1.0f);
    float cx  = __fadd_rn(r.x, __fmul_rn(0.5f, wdt));
    float cy  = __fadd_rn(r.y, __fmul_rn(0.5f, hgt));
    float gw  = __fadd_rn(__fsub_rn(gb.z, gb.x), 1.0f);
    float gh  = __fadd_rn(__fsub_rn(gb.w, gb.y), 1.0f);
    float gcx = __fadd_rn(gb.x, __fmul_rn(0.5f, gw));
    float gcy = __fadd_rn(gb.y, __fmul_rn(0.5f, gh));

    float d0 = __fdiv_rn(__fsub_rn(gcx, cx), wdt);
    float d1 = __fdiv_rn(__fsub_rn(gcy, cy), hgt);
    float d2 = logf(__fdiv_rn(gw, wdt));
    float d3 = logf(__fdiv_rn(gh, hgt));
    // (delta - MEAN)/STD with MEAN=0, STD=0.2
    d0 = __fdiv_rn(d0, 0.2f);
    d1 = __fdiv_rn(d1, 0.2f);
    d2 = __fdiv_rn(d2, 0.2f);
    d3 = __fdiv_rn(d3, 0.2f);

    out[4 * pos + 0] = r.x;
    out[4 * pos + 1] = r.y;
    out[4 * pos + 2] = r.z;
    out[4 * pos + 3] = r.w;
    out[2048 + 4 * pos + 0] = d0;
    out[2048 + 4 * pos + 1] = d1;
    out[2048 + 4 * pos + 2] = d2;
    out[2048 + 4 * pos + 3] = d3;
    out[4096 + pos] = (float)labels[g];
}

extern "C" void kernel_launch(void* const* d_in, const int* in_sizes, int n_in,
                              void* d_out, int out_size, void* d_ws, size_t ws_size,
                              hipStream_t stream)
{
    const float* rois   = (const float*)d_in[0];
    const float* gt     = (const float*)d_in[1];
    const int*   labels = (const int*)d_in[2];
    float* out = (float*)d_out;

    char* ws = (char*)d_ws;
    uint16_t* argmax  = (uint16_t*)(ws + OFF_ARGMAX);
    uint8_t*  flag    = (uint8_t*)(ws + OFF_FLAG);
    int*      blockFg = (int*)(ws + OFF_BLOCKFG);
    int*      blockBg = (int*)(ws + OFF_BLOCKBG);
    int*      fgOff   = (int*)(ws + OFF_FGOFF);
    int*      bgOff   = (int*)(ws + OFF_BGOFF);
    int*      params  = (int*)(ws + OFF_PARAMS);

    k_iou<<<NBLOCKS, BLK, 0, stream>>>(rois, gt, argmax, flag, blockFg, blockBg);
    k_scan<<<1, BLK, 0, stream>>>(blockFg, blockBg, fgOff, bgOff, params);
    k_select<<<NBLOCKS, BLK, 0, stream>>>(rois, gt, labels, argmax, flag,
                                          fgOff, bgOff, params, out);
}

// Round 2
// 40.577 us; speedup vs baseline: 1.1476x; 1.1476x over previous
//
#include <hip/hip_runtime.h>
#include <stdint.h>

#define N_PROP    262144
#define N_GT      128
#define N_ALL     (N_PROP + N_GT)      // 262272
#define NFG_MAX   128
#define NROIS_OUT 512
#define BLK       256
#define NBLOCKS   ((N_ALL + BLK - 1) / BLK)   // 1025

// ---------------- workspace layout (bytes) ----------------
// packed : uint16 [N_ALL]   @ 0        ((flag<<8)|argmax)
// cnt    : uint32 [NBLOCKS] @ 524544   ((bg<<16)|fg per block)
#define OFF_PACKED 0
#define OFF_CNT    524544

// K1: per-roi max/argmax IoU vs 128 GT; packed flag+argmax; per-block counts.
__global__ __launch_bounds__(BLK) void k_iou(
    const float* __restrict__ rois, const float* __restrict__ gt,
    uint16_t* __restrict__ packed, uint32_t* __restrict__ cnt)
{
    __shared__ float sgx1[N_GT], sgy1[N_GT], sgx2[N_GT], sgy2[N_GT], sga[N_GT];
    int tid = threadIdx.x;
    for (int j = tid; j < N_GT; j += BLK) {
        float4 g = *reinterpret_cast<const float4*>(gt + 4 * j);
        sgx1[j] = g.x; sgy1[j] = g.y; sgx2[j] = g.z; sgy2[j] = g.w;
        sga[j] = __fmul_rn(__fadd_rn(__fsub_rn(g.z, g.x), 1.0f),
                           __fadd_rn(__fsub_rn(g.w, g.y), 1.0f));
    }
    __syncthreads();

    int i = blockIdx.x * BLK + tid;
    bool valid = (i < N_ALL);
    float bx1 = 0.f, by1 = 0.f, bx2 = 0.f, by2 = 0.f;
    if (valid) {
        const float* p = (i < N_PROP) ? (rois + 4 * (size_t)i)
                                      : (gt + 4 * (size_t)(i - N_PROP));
        float4 b = *reinterpret_cast<const float4*>(p);
        bx1 = b.x; by1 = b.y; bx2 = b.z; by2 = b.w;
    }
    float area_b = __fmul_rn(__fadd_rn(__fsub_rn(bx2, bx1), 1.0f),
                             __fadd_rn(__fsub_rn(by2, by1), 1.0f));
    float best = -1.0f; int bestj = 0;
    if (valid) {
        #pragma unroll 4
        for (int j = 0; j < N_GT; ++j) {
            float iw = fmaxf(__fadd_rn(__fsub_rn(fminf(bx2, sgx2[j]), fmaxf(bx1, sgx1[j])), 1.0f), 0.0f);
            float ih = fmaxf(__fadd_rn(__fsub_rn(fminf(by2, sgy2[j]), fmaxf(by1, sgy1[j])), 1.0f), 0.0f);
            float inter = __fmul_rn(iw, ih);
            float denom = __fsub_rn(__fadd_rn(area_b, sga[j]), inter);
            float iou = __fdiv_rn(inter, denom);
            if (iou > best) { best = iou; bestj = j; }   // strict > == first-max (jnp.argmax)
        }
    }
    bool fg = valid && (best > 0.5f);
    bool bg = valid && (best > 0.1f) && (best < 0.5f);
    if (valid) {
        int flagv = fg ? 0 : (bg ? 1 : 2);
        packed[i] = (uint16_t)((flagv << 8) | bestj);
    }
    unsigned long long mf = __ballot(fg ? 1 : 0);
    unsigned long long mb = __ballot(bg ? 1 : 0);
    __shared__ int sF[BLK / 64], sB[BLK / 64];
    int lane = tid & 63, w = tid >> 6;
    if (lane == 0) { sF[w] = __popcll(mf); sB[w] = __popcll(mb); }
    __syncthreads();
    if (tid == 0) {
        int tf = 0, tb = 0;
        for (int k = 0; k < BLK / 64; ++k) { tf += sF[k]; tb += sB[k]; }
        cnt[blockIdx.x] = ((uint32_t)tb << 16) | (uint32_t)tf;
    }
}

// K2: per-block redundant global prefix over cnt[] + in-block ballot scan,
// then stable-argsort position reconstruction + gather + bbox_transform.
__global__ __launch_bounds__(BLK) void k_select(
    const float* __restrict__ rois, const float* __restrict__ gt,
    const int* __restrict__ labels,
    const uint16_t* __restrict__ packed, const uint32_t* __restrict__ cnt,
    float* __restrict__ out)
{
    int tid = threadIdx.x, bid = blockIdx.x;
    int i = bid * BLK + tid;
    bool valid = (i < N_ALL);
    uint16_t p = valid ? packed[i] : (uint16_t)(2 << 8);
    int flagv = p >> 8;
    int g = p & 0xFF;
    bool isfg = valid && (flagv == 0);
    bool isbg = valid && (flagv == 1);

    // ---- global totals + prefix(< bid) over block counts (redundant per block, L2-hot)
    int totF = 0, totB = 0, preF = 0, preB = 0;
    for (int j = tid; j < NBLOCKS; j += BLK) {
        uint32_t c = cnt[j];
        int f = (int)(c & 0xFFFFu), b = (int)(c >> 16);
        totF += f; totB += b;
        if (j < bid) { preF += f; preB += b; }
    }
    #pragma unroll
    for (int off = 32; off > 0; off >>= 1) {
        totF += __shfl_down(totF, off, 64);
        totB += __shfl_down(totB, off, 64);
        preF += __shfl_down(preF, off, 64);
        preB += __shfl_down(preB, off, 64);
    }
    __shared__ int sTF[4], sTB[4], sPF[4], sPB[4];
    __shared__ int sWF[4], sWB[4];
    int lane = tid & 63, w = tid >> 6;
    if (lane == 0) { sTF[w] = totF; sTB[w] = totB; sPF[w] = preF; sPB[w] = preB; }

    // ---- in-block ballot scan (independent of LDS above)
    unsigned long long mf = __ballot(isfg ? 1 : 0);
    unsigned long long mb = __ballot(isbg ? 1 : 0);
    unsigned long long lemask = (lane == 63) ? ~0ull : ((1ull << (lane + 1)) - 1ull);
    int inclF = __popcll(mf & lemask);
    int inclB = __popcll(mb & lemask);
    if (lane == 0) { sWF[w] = __popcll(mf); sWB[w] = __popcll(mb); }
    __syncthreads();

    totF = sTF[0] + sTF[1] + sTF[2] + sTF[3];
    totB = sTB[0] + sTB[1] + sTB[2] + sTB[3];
    preF = sPF[0] + sPF[1] + sPF[2] + sPF[3];
    preB = sPB[0] + sPB[1] + sPB[2] + sPB[3];
    int wPreF = 0, wPreB = 0;
    for (int k = 0; k < 4; ++k) {
        if (k < w) { wPreF += sWF[k]; wPreB += sWB[k]; }
    }
    if (!valid) return;

    int NF  = totF < NFG_MAX ? totF : NFG_MAX;
    int LIM = NROIS_OUT - NF;
    int NB  = totB < LIM ? totB : LIM;

    int fgCum = preF + wPreF + inclF;   // inclusive global fg cumsum at i
    int bgCum = preB + wPreB + inclB;

    int pos;
    if (isfg && fgCum <= NFG_MAX) {
        pos = fgCum - 1;
    } else if (isbg && bgCum <= LIM) {
        pos = NF + bgCum - 1;
    } else {
        int selF = fgCum < NFG_MAX ? fgCum : NFG_MAX;
        int selB = bgCum < LIM ? bgCum : LIM;
        int restCum = (i + 1) - selF - selB;
        pos = NF + NB + restCum - 1;
    }
    if (pos >= NROIS_OUT) return;

    const float* rp = (i < N_PROP) ? (rois + 4 * (size_t)i)
                                   : (gt + 4 * (size_t)(i - N_PROP));
    float4 r = *reinterpret_cast<const float4*>(rp);
    float4 gb = *reinterpret_cast<const float4*>(gt + 4 * (size_t)g);

    float wdt = __fadd_rn(__fsub_rn(r.z, r.x), 1.0f);
    float hgt = __fadd_rn(__fsub_rn(r.w, r.y), 1.0f);
    float cx  = __fadd_rn(r.x, __fmul_rn(0.5f, wdt));
    float cy  = __fadd_rn(r.y, __fmul_rn(0.5f, hgt));
    float gw  = __fadd_rn(__fsub_rn(gb.z, gb.x), 1.0f);
    float gh  = __fadd_rn(__fsub_rn(gb.w, gb.y), 1.0f);
    float gcx = __fadd_rn(gb.x, __fmul_rn(0.5f, gw));
    float gcy = __fadd_rn(gb.y, __fmul_rn(0.5f, gh));

    float d0 = __fdiv_rn(__fdiv_rn(__fsub_rn(gcx, cx), wdt), 0.2f);
    float d1 = __fdiv_rn(__fdiv_rn(__fsub_rn(gcy, cy), hgt), 0.2f);
    float d2 = __fdiv_rn(logf(__fdiv_rn(gw, wdt)), 0.2f);
    float d3 = __fdiv_rn(logf(__fdiv_rn(gh, hgt)), 0.2f);

    out[4 * pos + 0] = r.x;
    out[4 * pos + 1] = r.y;
    out[4 * pos + 2] = r.z;
    out[4 * pos + 3] = r.w;
    out[2048 + 4 * pos + 0] = d0;
    out[2048 + 4 * pos + 1] = d1;
    out[2048 + 4 * pos + 2] = d2;
    out[2048 + 4 * pos + 3] = d3;
    out[4096 + pos] = (float)labels[g];
}

extern "C" void kernel_launch(void* const* d_in, const int* in_sizes, int n_in,
                              void* d_out, int out_size, void* d_ws, size_t ws_size,
                              hipStream_t stream)
{
    const float* rois   = (const float*)d_in[0];
    const float* gt     = (const float*)d_in[1];
    const int*   labels = (const int*)d_in[2];
    float* out = (float*)d_out;

    char* ws = (char*)d_ws;
    uint16_t* packed = (uint16_t*)(ws + OFF_PACKED);
    uint32_t* cnt    = (uint32_t*)(ws + OFF_CNT);

    k_iou<<<NBLOCKS, BLK, 0, stream>>>(rois, gt, packed, cnt);
    k_select<<<NBLOCKS, BLK, 0, stream>>>(rois, gt, labels, packed, cnt, out);
}